// Round 11
// baseline (1291.125 us; speedup 1.0000x reference)
//
#include <hip/hip_runtime.h>
#include <hip/hip_bf16.h>
#include <cstdint>

#define CDIV(a,b) (((a)+(b)-1)/(b))

typedef short s8v __attribute__((ext_vector_type(8)));
typedef float f4v __attribute__((ext_vector_type(4)));
typedef float f2v __attribute__((ext_vector_type(2)));

// ---------------------------------------------------------------------
// helpers
// ---------------------------------------------------------------------
__device__ __forceinline__ unsigned short f2bf_bits(float v) {
  __hip_bfloat16 b = __float2bfloat16(v);
  unsigned short u; __builtin_memcpy(&u, &b, 2);
  return u;
}
__device__ __forceinline__ void bsplit(float v, unsigned short& h, unsigned short& l) {
  __hip_bfloat16 hb = __float2bfloat16(v);
  float hf = __bfloat162float(hb);
  unsigned short hu; __builtin_memcpy(&hu, &hb, 2);
  h = hu;
  l = f2bf_bits(v - hf);
}

// async global->LDS, 16B per lane; lds base must be wave-uniform.
__device__ __forceinline__ void gl2lds16(const void* g, void* l, int lane) {
#if __has_builtin(__builtin_amdgcn_global_load_lds)
  __builtin_amdgcn_global_load_lds(
      (const __attribute__((address_space(1))) unsigned int*)g,
      (__attribute__((address_space(3))) unsigned int*)l, 16, 0, 0);
#else
  ((uint4*)l)[lane] = *(const uint4*)g;
#endif
}

// AGPR pin: store/reload a float in an accumulator register (unified RF).
__device__ __forceinline__ void agpr_put(float& slot, float v) {
  asm volatile("v_accvgpr_write_b32 %0, %1" : "=a"(slot) : "v"(v));
}
__device__ __forceinline__ float agpr_get(const float& slot) {
  float v;
  asm volatile("v_accvgpr_read_b32 %0, %1" : "=v"(v) : "a"(slot));
  return v;
}

// packed 2xfp32 VALU (VOP3P)
__device__ __forceinline__ f2v pk_add(f2v a, f2v b) {
  f2v d; asm("v_pk_add_f32 %0, %1, %2" : "=v"(d) : "v"(a), "v"(b)); return d;
}
__device__ __forceinline__ f2v pk_mul(f2v a, f2v b) {
  f2v d; asm("v_pk_mul_f32 %0, %1, %2" : "=v"(d) : "v"(a), "v"(b)); return d;
}
__device__ __forceinline__ f2v pk_fma(f2v a, f2v b, f2v c) {
  f2v d; asm("v_pk_fma_f32 %0, %1, %2, %3" : "=v"(d) : "v"(a), "v"(b), "v"(c)); return d;
}

// ---------------------------------------------------------------------
// FPS — coords AGPR-pinned, packed fp32 distance math, key-only DPP
// argmax. NTHR=1024 for stage 1: 4 waves/SIMD hide the serial combine
// latency that stalled the 512-thread version (63% stall measured).
// Fused centroid gather epilogue writes AoS+SoA directly from LDS.
// ---------------------------------------------------------------------
template<int C>
__device__ __forceinline__ unsigned dpp32(unsigned v) {
  return (unsigned)__builtin_amdgcn_update_dpp((int)v, (int)v, C, 0xF, 0xF, false);
}
template<int C>
__device__ __forceinline__ unsigned long long red_key(unsigned long long pk) {
  unsigned lo = dpp32<C>((unsigned)pk);
  unsigned hi = dpp32<C>((unsigned)(pk >> 32));
  unsigned long long p2 = ((unsigned long long)hi << 32) | lo;
  return (p2 > pk) ? p2 : pk;
}

template<int NPTS, int MOUT, int NTHR>
__global__ __launch_bounds__(NTHR, 1) void fps_kernel(
    const float* __restrict__ pts, int bstride, int cstride,
    float* __restrict__ aos, float* __restrict__ soa)
{
  constexpr int PPT = NPTS / NTHR;   // must be even
  constexpr int NP2 = PPT / 2;
  constexpr int NW  = NTHR / 64;     // <= 16 (combine uses row_shr prefix)
  const int b = blockIdx.x, t = threadIdx.x;
  const int lane = t & 63;
  const int wid = t >> 6;
  const float* px = pts + (size_t)b * bstride;
  const float* py = px + cstride;
  const float* pz = px + 2 * cstride;
  __shared__ float s_x[NPTS], s_y[NPTS], s_z[NPTS];
  __shared__ unsigned long long s_key[2][NW > 1 ? NW : 1];
  __shared__ int s_out[MOUT];

  float ax[PPT], ay[PPT], az[PPT];   // AGPR-resident
  f2v dsv[NP2];                      // VGPR-resident (mutated)
#pragma unroll
  for (int j = 0; j < PPT; ++j) {
    int i = t + j * NTHR;
    float x = px[i], y = py[i], z = pz[i];
    s_x[i] = x; s_y[i] = y; s_z[i] = z;
    agpr_put(ax[j], x); agpr_put(ay[j], y); agpr_put(az[j], z);
  }
#pragma unroll
  for (int q = 0; q < NP2; ++q) dsv[q] = (f2v){1e10f, 1e10f};
  if (t == 0) s_out[0] = 0;
  float lx = px[0], ly = py[0], lz = pz[0];
  __syncthreads();

  for (int it = 1; it < MOUT; ++it) {
    const f2v nlx = (f2v){-lx, -lx};
    const f2v nly = (f2v){-ly, -ly};
    const f2v nlz = (f2v){-lz, -lz};
    float bestv = -1.0f; int bestj = 0;
#pragma unroll
    for (int q = 0; q < NP2; ++q) {
      f2v x2, y2, z2;
      x2.x = agpr_get(ax[2 * q]); x2.y = agpr_get(ax[2 * q + 1]);
      y2.x = agpr_get(ay[2 * q]); y2.y = agpr_get(ay[2 * q + 1]);
      z2.x = agpr_get(az[2 * q]); z2.y = agpr_get(az[2 * q + 1]);
      f2v dx = pk_add(x2, nlx);
      f2v dy = pk_add(y2, nly);
      f2v dz = pk_add(z2, nlz);
      f2v d2 = pk_fma(dz, dz, pk_fma(dy, dy, pk_mul(dx, dx)));
      float nd0 = fminf(dsv[q].x, d2.x);
      float nd1 = fminf(dsv[q].y, d2.y);
      dsv[q].x = nd0; dsv[q].y = nd1;
      if (nd0 > bestv) { bestv = nd0; bestj = 2 * q; }
      if (nd1 > bestv) { bestv = nd1; bestj = 2 * q + 1; }
    }
    const int besti = t + bestj * NTHR;   // global point index (NTHR-invariant key)
    unsigned long long pk =
        ((unsigned long long)__float_as_uint(bestv) << 32) | (unsigned)(~(unsigned)besti);
    pk = red_key<0x111>(pk);
    pk = red_key<0x112>(pk);
    pk = red_key<0x114>(pk);
    pk = red_key<0x118>(pk);
    pk = red_key<0x142>(pk);
    pk = red_key<0x143>(pk);
    int widx;
    if constexpr (NW == 1) {
      widx = (int)(~(unsigned)__builtin_amdgcn_readlane((int)(unsigned)pk, 63));
    } else {
      const int pb = it & 1;
      if (lane == 63) s_key[pb][wid] = pk;
      __syncthreads();
      unsigned long long ck = s_key[pb][lane & (NW - 1)];
      if (NW >= 2)  ck = red_key<0x111>(ck);
      if (NW >= 4)  ck = red_key<0x112>(ck);
      if (NW >= 8)  ck = red_key<0x114>(ck);
      if (NW >= 16) ck = red_key<0x118>(ck);
      widx = (int)(~(unsigned)__builtin_amdgcn_readlane((int)(unsigned)ck, NW - 1));
    }
    lx = s_x[widx]; ly = s_y[widx]; lz = s_z[widx];
    if (t == 0) s_out[it] = widx;
  }
  __syncthreads();
  // fused centroid gather: AoS + SoA straight from LDS
  for (int i = t; i < MOUT; i += NTHR) {
    const int idx = s_out[i];
    const float x = s_x[idx], y = s_y[idx], z = s_z[idx];
    float* a = aos + ((size_t)b * MOUT + i) * 3;
    a[0] = x; a[1] = y; a[2] = z;
    soa[(size_t)b * 3 * MOUT + i]            = x;
    soa[(size_t)b * 3 * MOUT + MOUT + i]     = y;
    soa[(size_t)b * 3 * MOUT + 2 * MOUT + i] = z;
  }
}

// ---------------- ball query — one wave per centroid ------------------
template<int NPTS, int KNB, int MC>
__global__ __launch_bounds__(64) void ballq_wave(
    const float* __restrict__ pts, int bstride, int cstride,
    const float* __restrict__ cents, int* __restrict__ out, float r2)
{
  constexpr int NCH = NPTS / 64;
  const int g = blockIdx.x;
  const int b = g / MC;
  const int lane = threadIdx.x;
  const float* px = pts + (size_t)b * bstride;
  const float* py = px + cstride;
  const float* pz = px + 2 * cstride;
  const float cx = cents[g * 3 + 0], cy = cents[g * 3 + 1], cz = cents[g * 3 + 2];
  __shared__ int s_idx[KNB];
  float nx = px[lane], ny = py[lane], nz = pz[lane];
  int base = 0;
  for (int c = 0; c < NCH; ++c) {
    float X = nx, Y = ny, Z = nz;
    if (c + 1 < NCH) {
      int i2 = (c + 1) * 64 + lane;
      nx = px[i2]; ny = py[i2]; nz = pz[i2];
    }
    float dx = X - cx, dy = Y - cy, dz = Z - cz;
    bool valid = (dx * dx + dy * dy + dz * dz) < r2;
    unsigned long long mask = __ballot(valid);
    int rank = __popcll(mask & ((1ull << lane) - 1ull));
    int pos = base + rank;
    if (valid && pos < KNB) s_idx[pos] = c * 64 + lane;
    base += __popcll(mask);
    if (base >= KNB) break;   // wave-uniform
  }
  int total = base < KNB ? base : KNB;   // >=1 (centroid hits itself)
  int first = s_idx[0];
  if (lane < KNB)
    out[(size_t)g * KNB + lane] = (lane < total) ? s_idx[lane] : first;
}

// ---------------------------------------------------------------------
// SA1 fully fused (unchanged from R9)
// ---------------------------------------------------------------------
__global__ __launch_bounds__(256, 1) void sa1_fused(
    const float* __restrict__ pts, const int* __restrict__ idx1,
    const float* __restrict__ cents,
    const float* __restrict__ w0, const float* __restrict__ b0,
    const unsigned short* __restrict__ w1h, const unsigned short* __restrict__ w1l,
    const float* __restrict__ b1,
    const unsigned short* __restrict__ w2h, const unsigned short* __restrict__ w2l,
    const float* __restrict__ b2,
    unsigned short* __restrict__ f1h, unsigned short* __restrict__ f1l)
{
  __shared__ __align__(16) unsigned short sY[2][128 * 72];
  __shared__ __align__(16) unsigned short sZ[2][128 * 72];
  __shared__ __align__(16) unsigned short sW[2][64 * 72];
  __shared__ float sw0[192];
  __shared__ float sb0[64];

  const int tid = threadIdx.x, lane = tid & 63, wid = tid >> 6;
  const int wm = wid & 1, wn = wid >> 1;
  const int mn15 = lane & 15, kgrp = lane >> 4;
  const int bk = blockIdx.x;

  if (tid < 192) sw0[tid] = w0[tid];
  else sb0[tid - 192] = b0[tid - 192];
  for (int gi = tid; gi < 1024; gi += 256) {
    const int pl = gi >> 9, idx = gi & 511;
    const int n = idx >> 3, k8 = idx & 7;
    const uint4 v = ((const uint4*)(pl ? w1l : w1h))[idx];
    *(uint4*)&sW[pl][n * 72 + k8 * 8] = v;
  }
  __syncthreads();

  {
    const int rl = tid >> 1, half = tid & 1;
    const int r = bk * 128 + rl;
    const int gl = r >> 5, j = r & 31, b = gl >> 9;
    const int i = idx1[(size_t)gl * 32 + j];
    const float* px = pts + (size_t)b * 24576;
    const float x = px[i]         - cents[gl * 3 + 0];
    const float y = px[8192 + i]  - cents[gl * 3 + 1];
    const float z = px[16384 + i] - cents[gl * 3 + 2];
    union { unsigned short us[32]; uint4 v[4]; } ph, pl4;
#pragma unroll
    for (int u = 0; u < 32; ++u) {
      const int o = half * 32 + u;
      float v = sw0[o * 3] * x + sw0[o * 3 + 1] * y + sw0[o * 3 + 2] * z + sb0[o];
      v = fmaxf(v, 0.f);
      bsplit(v, ph.us[u], pl4.us[u]);
    }
    const int base = rl * 72 + half * 32;
#pragma unroll
    for (int g = 0; g < 4; ++g) {
      *(uint4*)&sY[0][base + g * 8] = ph.v[g];
      *(uint4*)&sY[1][base + g * 8] = pl4.v[g];
    }
  }
  __syncthreads();

  {
    f4v acc[4][2];
#pragma unroll
    for (int a = 0; a < 4; ++a)
#pragma unroll
      for (int c = 0; c < 2; ++c) acc[a][c] = (f4v){0.f, 0.f, 0.f, 0.f};
#pragma unroll
    for (int kc = 0; kc < 2; ++kc) {
      const int k0 = kc * 32;
      s8v af[2][4], bf[2][2];
#pragma unroll
      for (int mt = 0; mt < 4; ++mt) {
        const int m = wm * 64 + mt * 16 + mn15;
        af[0][mt] = *(const s8v*)&sY[0][m * 72 + k0 + kgrp * 8];
        af[1][mt] = *(const s8v*)&sY[1][m * 72 + k0 + kgrp * 8];
      }
#pragma unroll
      for (int nt = 0; nt < 2; ++nt) {
        const int n = wn * 32 + nt * 16 + mn15;
        bf[0][nt] = *(const s8v*)&sW[0][n * 72 + k0 + kgrp * 8];
        bf[1][nt] = *(const s8v*)&sW[1][n * 72 + k0 + kgrp * 8];
      }
#pragma unroll
      for (int mt = 0; mt < 4; ++mt)
#pragma unroll
        for (int nt = 0; nt < 2; ++nt) {
          acc[mt][nt] = __builtin_amdgcn_mfma_f32_16x16x32_bf16(af[0][mt], bf[0][nt], acc[mt][nt], 0, 0, 0);
          acc[mt][nt] = __builtin_amdgcn_mfma_f32_16x16x32_bf16(af[0][mt], bf[1][nt], acc[mt][nt], 0, 0, 0);
          acc[mt][nt] = __builtin_amdgcn_mfma_f32_16x16x32_bf16(af[1][mt], bf[0][nt], acc[mt][nt], 0, 0, 0);
        }
    }
#pragma unroll
    for (int nt = 0; nt < 2; ++nt) {
      const int n = wn * 32 + nt * 16 + mn15;
      const float bv = b1[n];
#pragma unroll
      for (int mt = 0; mt < 4; ++mt)
#pragma unroll
        for (int r = 0; r < 4; ++r) {
          const int m = wm * 64 + mt * 16 + (lane >> 4) * 4 + r;
          float v = fmaxf(acc[mt][nt][r] + bv, 0.f);
          unsigned short h, l; bsplit(v, h, l);
          sZ[0][m * 72 + n] = h;
          sZ[1][m * 72 + n] = l;
        }
    }
  }
  __syncthreads();

  for (int gi = tid; gi < 2048; gi += 256) {
    const int pl = gi >> 10, idx = gi & 1023;
    const int n = idx >> 3, k8 = idx & 7;
    const uint4 v = ((const uint4*)(pl ? w2l : w2h))[idx];
    *(uint4*)&sY[pl][n * 72 + k8 * 8] = v;
  }
  __syncthreads();

  {
    f4v acc[4][4];
#pragma unroll
    for (int a = 0; a < 4; ++a)
#pragma unroll
      for (int c = 0; c < 4; ++c) acc[a][c] = (f4v){0.f, 0.f, 0.f, 0.f};
#pragma unroll
    for (int kc = 0; kc < 2; ++kc) {
      const int k0 = kc * 32;
      s8v af[2][4], bf[2][4];
#pragma unroll
      for (int mt = 0; mt < 4; ++mt) {
        const int m = wm * 64 + mt * 16 + mn15;
        af[0][mt] = *(const s8v*)&sZ[0][m * 72 + k0 + kgrp * 8];
        af[1][mt] = *(const s8v*)&sZ[1][m * 72 + k0 + kgrp * 8];
      }
#pragma unroll
      for (int nt = 0; nt < 4; ++nt) {
        const int n = wn * 64 + nt * 16 + mn15;
        bf[0][nt] = *(const s8v*)&sY[0][n * 72 + k0 + kgrp * 8];
        bf[1][nt] = *(const s8v*)&sY[1][n * 72 + k0 + kgrp * 8];
      }
#pragma unroll
      for (int mt = 0; mt < 4; ++mt)
#pragma unroll
        for (int nt = 0; nt < 4; ++nt) {
          acc[mt][nt] = __builtin_amdgcn_mfma_f32_16x16x32_bf16(af[0][mt], bf[0][nt], acc[mt][nt], 0, 0, 0);
          acc[mt][nt] = __builtin_amdgcn_mfma_f32_16x16x32_bf16(af[0][mt], bf[1][nt], acc[mt][nt], 0, 0, 0);
          acc[mt][nt] = __builtin_amdgcn_mfma_f32_16x16x32_bf16(af[1][mt], bf[0][nt], acc[mt][nt], 0, 0, 0);
        }
    }
#pragma unroll
    for (int gq = 0; gq < 2; ++gq)
#pragma unroll
      for (int nt = 0; nt < 4; ++nt) {
        const int n = wn * 64 + nt * 16 + mn15;
        float v = -1e30f;
#pragma unroll
        for (int mt = 2 * gq; mt < 2 * gq + 2; ++mt)
#pragma unroll
          for (int r = 0; r < 4; ++r) v = fmaxf(v, acc[mt][nt][r]);
        v = fmaxf(v + b2[n], 0.f);
        v = fmaxf(v, __shfl_xor(v, 16, 64));
        v = fmaxf(v, __shfl_xor(v, 32, 64));
        if (lane < 16) {
          const size_t row = (size_t)bk * 4 + wm * 2 + gq;
          unsigned short h, l; bsplit(v, h, l);
          f1h[row * 128 + n] = h;
          f1l[row * 128 + n] = l;
        }
      }
  }
}

// ---------------------------------------------------------------------
// SA2 fully fused (unchanged from R10)
// ---------------------------------------------------------------------
__global__ __launch_bounds__(256, 1) void sa2_fused(
    const unsigned short* __restrict__ f1h, const unsigned short* __restrict__ f1l,
    const float* __restrict__ nx1_aos, const float* __restrict__ nx2_aos,
    const int* __restrict__ idx2,
    const unsigned short* __restrict__ w1h, const unsigned short* __restrict__ w1l,
    const float* __restrict__ b1,
    const unsigned short* __restrict__ w2h, const unsigned short* __restrict__ w2l,
    const float* __restrict__ b2,
    const unsigned short* __restrict__ w3h, const unsigned short* __restrict__ w3l,
    const float* __restrict__ b3,
    unsigned short* __restrict__ f2h, unsigned short* __restrict__ f2l)
{
  __shared__ __align__(16) unsigned short sX[2][64 * 160];  // X; later Z (stride 136)
  __shared__ __align__(16) unsigned short sY[2][64 * 136];
  __shared__ __align__(16) unsigned short sW[4][2][32 * 40]; // per-wave W regions

  const int tid = threadIdx.x, lane = tid & 63, wid = tid >> 6;
  const int mn15 = lane & 15, kgrp = lane >> 4;
  const int gg = blockIdx.x;
  const int bb = gg >> 7;

  {
    const int r = tid >> 2, q = tid & 3;
    const int i = idx2[(size_t)gg * 64 + r];
    const int p = bb * 512 + i;
#pragma unroll
    for (int pl = 0; pl < 2; ++pl) {
      const uint4* src = (const uint4*)((pl ? f1l : f1h) + (size_t)p * 128);
#pragma unroll
      for (int g = 0; g < 4; ++g)
        *(uint4*)&sX[pl][r * 160 + (q * 4 + g) * 8] = src[q * 4 + g];
    }
    if (q == 0) {
      union { unsigned short us[8]; uint4 v; } ph, pl4;
#pragma unroll
      for (int u = 0; u < 8; ++u) { ph.us[u] = 0; pl4.us[u] = 0; }
#pragma unroll
      for (int c = 0; c < 3; ++c) {
        float v = nx1_aos[(size_t)p * 3 + c] - nx2_aos[(size_t)gg * 3 + c];
        bsplit(v, ph.us[c], pl4.us[c]);
      }
      *(uint4*)&sX[0][r * 160 + 128] = ph.v;
      *(uint4*)&sX[1][r * 160 + 128] = pl4.v;
    } else {
      uint4 z = make_uint4(0, 0, 0, 0);
      *(uint4*)&sX[0][r * 160 + 128 + q * 8] = z;
      *(uint4*)&sX[1][r * 160 + 128 + q * 8] = z;
    }
  }
  __syncthreads();

  const int spl = lane >> 5, srow = lane & 31;
  unsigned short* swb = &sW[wid][0][0];

  // ============ L1: 64x128, K=160 (5 chunks) ============
  {
    f4v acc[4][2];
#pragma unroll
    for (int a = 0; a < 4; ++a)
#pragma unroll
      for (int c = 0; c < 2; ++c) acc[a][c] = (f4v){0.f, 0.f, 0.f, 0.f};
    uint4 pf[4];
    {
      const unsigned short* s = (spl ? w1l : w1h) + (size_t)(wid * 32 + srow) * 160;
#pragma unroll
      for (int g = 0; g < 4; ++g) pf[g] = *(const uint4*)(s + g * 8);
    }
#pragma unroll
    for (int c = 0; c < 5; ++c) {
      unsigned short* d = swb + spl * 1280 + srow * 40;
#pragma unroll
      for (int g = 0; g < 4; ++g) *(uint4*)(d + g * 8) = pf[g];
      if (c < 4) {
        const unsigned short* s = (spl ? w1l : w1h) + (size_t)(wid * 32 + srow) * 160 + (c + 1) * 32;
#pragma unroll
        for (int g = 0; g < 4; ++g) pf[g] = *(const uint4*)(s + g * 8);
      }
      const int k0 = c * 32;
      s8v af[2][4], bf[2][2];
#pragma unroll
      for (int mt = 0; mt < 4; ++mt) {
        const int m = mt * 16 + mn15;
        af[0][mt] = *(const s8v*)&sX[0][m * 160 + k0 + kgrp * 8];
        af[1][mt] = *(const s8v*)&sX[1][m * 160 + k0 + kgrp * 8];
      }
#pragma unroll
      for (int nt = 0; nt < 2; ++nt) {
        const int nl = nt * 16 + mn15;
        bf[0][nt] = *(const s8v*)&swb[0 * 1280 + nl * 40 + kgrp * 8];
        bf[1][nt] = *(const s8v*)&swb[1 * 1280 + nl * 40 + kgrp * 8];
      }
#pragma unroll
      for (int mt = 0; mt < 4; ++mt)
#pragma unroll
        for (int nt = 0; nt < 2; ++nt) {
          acc[mt][nt] = __builtin_amdgcn_mfma_f32_16x16x32_bf16(af[0][mt], bf[0][nt], acc[mt][nt], 0, 0, 0);
          acc[mt][nt] = __builtin_amdgcn_mfma_f32_16x16x32_bf16(af[0][mt], bf[1][nt], acc[mt][nt], 0, 0, 0);
          acc[mt][nt] = __builtin_amdgcn_mfma_f32_16x16x32_bf16(af[1][mt], bf[0][nt], acc[mt][nt], 0, 0, 0);
        }
    }
#pragma unroll
    for (int nt = 0; nt < 2; ++nt) {
      const int n = wid * 32 + nt * 16 + mn15;
      const float bv = b1[n];
#pragma unroll
      for (int mt = 0; mt < 4; ++mt)
#pragma unroll
        for (int r = 0; r < 4; ++r) {
          const int m = mt * 16 + kgrp * 4 + r;
          float v = fmaxf(acc[mt][nt][r] + bv, 0.f);
          unsigned short h, l; bsplit(v, h, l);
          sY[0][m * 136 + n] = h;
          sY[1][m * 136 + n] = l;
        }
    }
  }
  __syncthreads();

  // ============ L2: 64x128, K=128 (4 chunks), out -> Z (overlay sX) ===
  {
    f4v acc[4][2];
#pragma unroll
    for (int a = 0; a < 4; ++a)
#pragma unroll
      for (int c = 0; c < 2; ++c) acc[a][c] = (f4v){0.f, 0.f, 0.f, 0.f};
    uint4 pf[4];
    {
      const unsigned short* s = (spl ? w2l : w2h) + (size_t)(wid * 32 + srow) * 128;
#pragma unroll
      for (int g = 0; g < 4; ++g) pf[g] = *(const uint4*)(s + g * 8);
    }
#pragma unroll
    for (int c = 0; c < 4; ++c) {
      unsigned short* d = swb + spl * 1280 + srow * 40;
#pragma unroll
      for (int g = 0; g < 4; ++g) *(uint4*)(d + g * 8) = pf[g];
      if (c < 3) {
        const unsigned short* s = (spl ? w2l : w2h) + (size_t)(wid * 32 + srow) * 128 + (c + 1) * 32;
#pragma unroll
        for (int g = 0; g < 4; ++g) pf[g] = *(const uint4*)(s + g * 8);
      }
      const int k0 = c * 32;
      s8v af[2][4], bf[2][2];
#pragma unroll
      for (int mt = 0; mt < 4; ++mt) {
        const int m = mt * 16 + mn15;
        af[0][mt] = *(const s8v*)&sY[0][m * 136 + k0 + kgrp * 8];
        af[1][mt] = *(const s8v*)&sY[1][m * 136 + k0 + kgrp * 8];
      }
#pragma unroll
      for (int nt = 0; nt < 2; ++nt) {
        const int nl = nt * 16 + mn15;
        bf[0][nt] = *(const s8v*)&swb[0 * 1280 + nl * 40 + kgrp * 8];
        bf[1][nt] = *(const s8v*)&swb[1 * 1280 + nl * 40 + kgrp * 8];
      }
#pragma unroll
      for (int mt = 0; mt < 4; ++mt)
#pragma unroll
        for (int nt = 0; nt < 2; ++nt) {
          acc[mt][nt] = __builtin_amdgcn_mfma_f32_16x16x32_bf16(af[0][mt], bf[0][nt], acc[mt][nt], 0, 0, 0);
          acc[mt][nt] = __builtin_amdgcn_mfma_f32_16x16x32_bf16(af[0][mt], bf[1][nt], acc[mt][nt], 0, 0, 0);
          acc[mt][nt] = __builtin_amdgcn_mfma_f32_16x16x32_bf16(af[1][mt], bf[0][nt], acc[mt][nt], 0, 0, 0);
        }
    }
#pragma unroll
    for (int nt = 0; nt < 2; ++nt) {
      const int n = wid * 32 + nt * 16 + mn15;
      const float bv = b2[n];
#pragma unroll
      for (int mt = 0; mt < 4; ++mt)
#pragma unroll
        for (int r = 0; r < 4; ++r) {
          const int m = mt * 16 + kgrp * 4 + r;
          float v = fmaxf(acc[mt][nt][r] + bv, 0.f);
          unsigned short h, l; bsplit(v, h, l);
          sX[0][m * 136 + n] = h;
          sX[1][m * 136 + n] = l;
        }
    }
  }
  __syncthreads();

  // ============ L3: 64x256, K=128, two 32-col halves + pool-64 ========
#pragma unroll
  for (int h = 0; h < 2; ++h) {
    f4v acc[4][2];
#pragma unroll
    for (int a = 0; a < 4; ++a)
#pragma unroll
      for (int c = 0; c < 2; ++c) acc[a][c] = (f4v){0.f, 0.f, 0.f, 0.f};
    const int nb = wid * 64 + h * 32;
    uint4 pf[4];
    {
      const unsigned short* s = (spl ? w3l : w3h) + (size_t)(nb + srow) * 128;
#pragma unroll
      for (int g = 0; g < 4; ++g) pf[g] = *(const uint4*)(s + g * 8);
    }
#pragma unroll
    for (int c = 0; c < 4; ++c) {
      unsigned short* d = swb + spl * 1280 + srow * 40;
#pragma unroll
      for (int g = 0; g < 4; ++g) *(uint4*)(d + g * 8) = pf[g];
      if (c < 3) {
        const unsigned short* s = (spl ? w3l : w3h) + (size_t)(nb + srow) * 128 + (c + 1) * 32;
#pragma unroll
        for (int g = 0; g < 4; ++g) pf[g] = *(const uint4*)(s + g * 8);
      }
      const int k0 = c * 32;
      s8v af[2][4], bf[2][2];
#pragma unroll
      for (int mt = 0; mt < 4; ++mt) {
        const int m = mt * 16 + mn15;
        af[0][mt] = *(const s8v*)&sX[0][m * 136 + k0 + kgrp * 8];
        af[1][mt] = *(const s8v*)&sX[1][m * 136 + k0 + kgrp * 8];
      }
#pragma unroll
      for (int nt = 0; nt < 2; ++nt) {
        const int nl = nt * 16 + mn15;
        bf[0][nt] = *(const s8v*)&swb[0 * 1280 + nl * 40 + kgrp * 8];
        bf[1][nt] = *(const s8v*)&swb[1 * 1280 + nl * 40 + kgrp * 8];
      }
#pragma unroll
      for (int mt = 0; mt < 4; ++mt)
#pragma unroll
        for (int nt = 0; nt < 2; ++nt) {
          acc[mt][nt] = __builtin_amdgcn_mfma_f32_16x16x32_bf16(af[0][mt], bf[0][nt], acc[mt][nt], 0, 0, 0);
          acc[mt][nt] = __builtin_amdgcn_mfma_f32_16x16x32_bf16(af[0][mt], bf[1][nt], acc[mt][nt], 0, 0, 0);
          acc[mt][nt] = __builtin_amdgcn_mfma_f32_16x16x32_bf16(af[1][mt], bf[0][nt], acc[mt][nt], 0, 0, 0);
        }
    }
#pragma unroll
    for (int nt = 0; nt < 2; ++nt) {
      const int n = nb + nt * 16 + mn15;
      float v = -1e30f;
#pragma unroll
      for (int mt = 0; mt < 4; ++mt)
#pragma unroll
        for (int r = 0; r < 4; ++r) v = fmaxf(v, acc[mt][nt][r]);
      v = fmaxf(v + b3[n], 0.f);
      v = fmaxf(v, __shfl_xor(v, 16, 64));
      v = fmaxf(v, __shfl_xor(v, 32, 64));
      if (lane < 16) {
        unsigned short hh, ll; bsplit(v, hh, ll);
        f2h[(size_t)gg * 256 + n] = hh;
        f2l[(size_t)gg * 256 + n] = ll;
      }
    }
  }
}

// ------------- all weight fp32 -> hi/lo splits in ONE launch -----------
struct WSplitArgs {
  const float* src[9];
  unsigned short* h[9];
  unsigned short* l[9];
  int K[9];
  int KP[9];
  int perm[9];
  int cum[10];
};
__global__ void wsplit_all(WSplitArgs a) {
  int i = blockIdx.x * 256 + threadIdx.x;
  if (i >= a.cum[9]) return;
  int s = 0;
#pragma unroll
  for (int t = 1; t < 9; ++t) s += (i >= a.cum[t]);
  int local = i - a.cum[s];
  int KP = a.KP[s], K = a.K[s];
  int r = local / KP, k = local - r * KP;
  int oc;
  if (a.perm[s]) oc = (k < 128) ? k + 3 : (k < 131 ? k - 128 : -1);
  else           oc = (k < K) ? k : -1;
  float v = (oc >= 0) ? a.src[s][(size_t)r * K + oc] : 0.f;
  unsigned short hb, lb; bsplit(v, hb, lb);
  a.h[s][local] = hb; a.l[s][local] = lb;
}

// ---------------------------------------------------------------------
// MFMA GEMM (loc MLP only)
// ---------------------------------------------------------------------
template<int BN, int POOL>
__global__ __launch_bounds__(256, 1) void mfma_gemm(
    const unsigned short* __restrict__ Ah, const unsigned short* __restrict__ Al,
    const unsigned short* __restrict__ Wh, const unsigned short* __restrict__ Wl,
    const float* __restrict__ bias,
    unsigned short* __restrict__ Ch, unsigned short* __restrict__ Cl,
    float* __restrict__ Cf,
    unsigned short* __restrict__ Chp, unsigned short* __restrict__ Clp,
    int Kdim, int Ndim)
{
  constexpr int WTN = BN / 2, NT = WTN / 16;
  __shared__ unsigned short sA[2][128 * 32];
  __shared__ unsigned short sW[2][BN * 32];
  __shared__ float sPool[4][WTN];
  const int tid = threadIdx.x, lane = tid & 63, wid = tid >> 6;
  const int wm = wid & 1, wn = wid >> 1;
  const size_t bm0 = (size_t)blockIdx.y * 128;
  const int bn0 = blockIdx.x * BN;
  const int mn15 = lane & 15, kgrp = lane >> 4;

  f4v acc[4][NT];
#pragma unroll
  for (int a = 0; a < 4; ++a)
#pragma unroll
    for (int b = 0; b < NT; ++b) acc[a][b] = (f4v){0.f, 0.f, 0.f, 0.f};

  const int sc = lane & 3, srl = lane >> 2;

  for (int k0 = 0; k0 < Kdim; k0 += 32) {
#pragma unroll
    for (int hh = 0; hh < 2; ++hh) {
      const int R = wid * 32 + hh * 16;
      const int m = R + srl;
      const int kg = (sc - m - (m >> 2)) & 3;
      const size_t go = (bm0 + m) * (size_t)Kdim + k0 + kg * 8;
      gl2lds16(Ah + go, &sA[0][R * 32], lane);
      gl2lds16(Al + go, &sA[1][R * 32], lane);
    }
    if (BN == 128) {
#pragma unroll
      for (int hh = 0; hh < 2; ++hh) {
        const int R = wid * 32 + hh * 16;
        const int n = R + srl;
        const int kg = (sc - n - (n >> 2)) & 3;
        const size_t go = (size_t)(bn0 + n) * Kdim + k0 + kg * 8;
        gl2lds16(Wh + go, &sW[0][R * 32], lane);
        gl2lds16(Wl + go, &sW[1][R * 32], lane);
      }
    } else {
      const int R = wid * 16;
      const int n = R + srl;
      const int kg = (sc - n - (n >> 2)) & 3;
      const size_t go = (size_t)(bn0 + n) * Kdim + k0 + kg * 8;
      gl2lds16(Wh + go, &sW[0][R * 32], lane);
      gl2lds16(Wl + go, &sW[1][R * 32], lane);
    }
    __syncthreads();

    s8v af[2][4], bfr[2][NT];
#pragma unroll
    for (int mt = 0; mt < 4; ++mt) {
      const int m = wm * 64 + mt * 16 + mn15;
      const int cc = (kgrp + m + (m >> 2)) & 3;
      af[0][mt] = *(const s8v*)&sA[0][m * 32 + cc * 8];
      af[1][mt] = *(const s8v*)&sA[1][m * 32 + cc * 8];
    }
#pragma unroll
    for (int nt = 0; nt < NT; ++nt) {
      const int n = wn * WTN + nt * 16 + mn15;
      const int cc = (kgrp + n + (n >> 2)) & 3;
      bfr[0][nt] = *(const s8v*)&sW[0][n * 32 + cc * 8];
      bfr[1][nt] = *(const s8v*)&sW[1][n * 32 + cc * 8];
    }
#pragma unroll
    for (int mt = 0; mt < 4; ++mt)
#pragma unroll
      for (int nt = 0; nt < NT; ++nt) {
        acc[mt][nt] = __builtin_amdgcn_mfma_f32_16x16x32_bf16(af[0][mt], bfr[0][nt], acc[mt][nt], 0, 0, 0);
        acc[mt][nt] = __builtin_amdgcn_mfma_f32_16x16x32_bf16(af[0][mt], bfr[1][nt], acc[mt][nt], 0, 0, 0);
        acc[mt][nt] = __builtin_amdgcn_mfma_f32_16x16x32_bf16(af[1][mt], bfr[0][nt], acc[mt][nt], 0, 0, 0);
      }
    __syncthreads();
  }

  float bv[NT];
#pragma unroll
  for (int nt = 0; nt < NT; ++nt) bv[nt] = bias[bn0 + wn * WTN + nt * 16 + mn15];

  if (POOL == 0) {
#pragma unroll
    for (int mt = 0; mt < 4; ++mt)
#pragma unroll
      for (int nt = 0; nt < NT; ++nt) {
        const int n = bn0 + wn * WTN + nt * 16 + mn15;
#pragma unroll
        for (int r = 0; r < 4; ++r) {
          const size_t m = bm0 + wm * 64 + mt * 16 + (lane >> 4) * 4 + r;
          float v = fmaxf(acc[mt][nt][r] + bv[nt], 0.f);
          unsigned short h, l; bsplit(v, h, l);
          Ch[m * Ndim + n] = h;
          Cl[m * Ndim + n] = l;
        }
      }
  } else {  // POOL == 128 (loc L3)
    float part[NT];
#pragma unroll
    for (int nt = 0; nt < NT; ++nt) {
      float v = -1e30f;
#pragma unroll
      for (int mt = 0; mt < 4; ++mt)
#pragma unroll
        for (int r = 0; r < 4; ++r) v = fmaxf(v, acc[mt][nt][r]);
      v = fmaxf(v + bv[nt], 0.f);
      v = fmaxf(v, __shfl_xor(v, 16, 64));
      v = fmaxf(v, __shfl_xor(v, 32, 64));
      part[nt] = v;
      if (lane < 16) sPool[wid][nt * 16 + mn15] = v;
    }
    __syncthreads();
    if (wm == 0 && lane < 16) {
#pragma unroll
      for (int nt = 0; nt < NT; ++nt) {
        float v = fmaxf(part[nt], sPool[wid + 1][nt * 16 + mn15]);
        const int n = bn0 + wn * WTN + nt * 16 + mn15;
        if (Cf) Cf[(size_t)(bm0 / 128) * Ndim + n] = v;
      }
    }
  }
}

// ------------- fused head: glob0 -> glob1 -> cls, 1 block/batch --------
__global__ __launch_bounds__(256) void head_kernel(
    const float* __restrict__ pooled,
    const float* __restrict__ w0, const float* __restrict__ b0,
    const float* __restrict__ w1, const float* __restrict__ b1,
    const float* __restrict__ wc, const float* __restrict__ bc,
    float* __restrict__ out)
{
  __shared__ float sx[1024];
  __shared__ float sy[512];
  __shared__ float sz[256];
  const int b = blockIdx.x, t = threadIdx.x;
  for (int i = t; i < 1024; i += 256) sx[i] = pooled[(size_t)b * 1024 + i];
  __syncthreads();
  for (int o = t; o < 512; o += 256) {
    const float4* w4 = (const float4*)(w0 + (size_t)o * 1024);
    const float4* x4 = (const float4*)sx;
    float acc = 0.f;
#pragma unroll 4
    for (int k = 0; k < 256; ++k) {
      float4 w = w4[k], x = x4[k];
      acc += w.x * x.x + w.y * x.y + w.z * x.z + w.w * x.w;
    }
    sy[o] = fmaxf(acc + b0[o], 0.f);
  }
  __syncthreads();
  if (t < 256) {
    const float4* w4 = (const float4*)(w1 + (size_t)t * 512);
    const float4* y4 = (const float4*)sy;
    float acc = 0.f;
#pragma unroll 4
    for (int k = 0; k < 128; ++k) {
      float4 w = w4[k], y = y4[k];
      acc += w.x * y.x + w.y * y.y + w.z * y.z + w.w * y.w;
    }
    sz[t] = fmaxf(acc + b1[t], 0.f);
  }
  __syncthreads();
  if (t < 40) {
    const float4* w4 = (const float4*)(wc + (size_t)t * 256);
    const float4* z4 = (const float4*)sz;
    float acc = 0.f;
#pragma unroll 4
    for (int k = 0; k < 64; ++k) {
      float4 w = w4[k], z = z4[k];
      acc += w.x * z.x + w.y * z.y + w.z * z.z + w.w * z.w;
    }
    out[(size_t)b * 40 + t] = acc + bc[t];
  }
}

// =====================================================================
extern "C" void kernel_launch(void* const* d_in, const int* in_sizes, int n_in,
                              void* d_out, int out_size, void* d_ws, size_t ws_size,
                              hipStream_t stream)
{
  (void)in_sizes; (void)n_in; (void)out_size; (void)ws_size;

  const float* points  = (const float*)d_in[0];
  const float* sa1_w[3] = {(const float*)d_in[1], (const float*)d_in[3], (const float*)d_in[5]};
  const float* sa1_b[3] = {(const float*)d_in[2], (const float*)d_in[4], (const float*)d_in[6]};
  const float* sa2_w[3] = {(const float*)d_in[7], (const float*)d_in[9], (const float*)d_in[11]};
  const float* sa2_b[3] = {(const float*)d_in[8], (const float*)d_in[10], (const float*)d_in[12]};
  const float* loc_w[3] = {(const float*)d_in[13], (const float*)d_in[15], (const float*)d_in[17]};
  const float* loc_b[3] = {(const float*)d_in[14], (const float*)d_in[16], (const float*)d_in[18]};
  const float* glob_w0 = (const float*)d_in[19];
  const float* glob_b0 = (const float*)d_in[20];
  const float* glob_w1 = (const float*)d_in[21];
  const float* glob_b1 = (const float*)d_in[22];
  const float* cls_w   = (const float*)d_in[23];
  const float* cls_b   = (const float*)d_in[24];

  char* base = (char*)d_ws;
  size_t off = 0;
  auto alloc = [&](size_t nbytes) -> void* {
    void* p = base + off;
    off += (nbytes + 255) & ~(size_t)255;
    return p;
  };

  // loc ping-pong plane buffers
  const size_t XE = (size_t)4096 * 512;
  const size_t YE = (size_t)4096 * 256;
  unsigned short* Xh = (unsigned short*)alloc(XE * 2);
  unsigned short* Xl = (unsigned short*)alloc(XE * 2);
  unsigned short* Yh = (unsigned short*)alloc(YE * 2);
  unsigned short* Yl = (unsigned short*)alloc(YE * 2);
  unsigned short* f1h = (unsigned short*)alloc((size_t)16384 * 128 * 2);
  unsigned short* f1l = (unsigned short*)alloc((size_t)16384 * 128 * 2);
  unsigned short* f2h = (unsigned short*)alloc((size_t)4096 * 256 * 2);
  unsigned short* f2l = (unsigned short*)alloc((size_t)4096 * 256 * 2);

  // weight planes
  const int  wrows[9] = {64, 64, 128, 128, 128, 256, 256, 512, 1024};
  const int  wK[9]    = {3, 64, 64, 131, 128, 128, 256, 256, 512};
  const int  wKP[9]   = {32, 64, 64, 160, 128, 128, 256, 256, 512};
  const float* wsrc[9] = {sa1_w[0], sa1_w[1], sa1_w[2],
                          sa2_w[0], sa2_w[1], sa2_w[2],
                          loc_w[0], loc_w[1], loc_w[2]};
  unsigned short *wph[9], *wpl[9];
  WSplitArgs wa;
  int cum = 0;
  for (int s = 0; s < 9; ++s) {
    size_t e = (size_t)wrows[s] * wKP[s];
    wph[s] = (unsigned short*)alloc(e * 2);
    wpl[s] = (unsigned short*)alloc(e * 2);
    wa.src[s] = wsrc[s]; wa.h[s] = wph[s]; wa.l[s] = wpl[s];
    wa.K[s] = wK[s]; wa.KP[s] = wKP[s]; wa.cum[s] = cum;
    wa.perm[s] = (s == 3) ? 1 : 0;
    cum += wrows[s] * wKP[s];
  }
  wa.cum[9] = cum;

  float* nx1_aos = (float*)alloc((size_t)32 * 512 * 3 * 4);
  float* nx1_soa = (float*)alloc((size_t)32 * 512 * 3 * 4);
  int*   idx1    = (int*)  alloc((size_t)32 * 512 * 32 * 4);
  float* nx2_aos = (float*)alloc((size_t)32 * 128 * 3 * 4);
  float* nx2_soa = (float*)alloc((size_t)32 * 128 * 3 * 4);
  int*   idx2    = (int*)  alloc((size_t)32 * 128 * 64 * 4);
  float* pooled  = (float*)alloc((size_t)32 * 1024 * 4);

  const float r2a = (float)(0.2 * 0.2);
  const float r2b = (float)(0.4 * 0.4);

  wsplit_all<<<CDIV(cum, 256), 256, 0, stream>>>(wa);

  // ---------------- SA1 ----------------
  fps_kernel<8192, 512, 1024><<<32, 1024, 0, stream>>>(points, 24576, 8192, nx1_aos, nx1_soa);
  ballq_wave<8192, 32, 512><<<32 * 512, 64, 0, stream>>>(points, 24576, 8192, nx1_aos, idx1, r2a);

  sa1_fused<<<4096, 256, 0, stream>>>(
      points, idx1, nx1_aos, sa1_w[0], sa1_b[0],
      wph[1], wpl[1], sa1_b[1], wph[2], wpl[2], sa1_b[2], f1h, f1l);

  // ---------------- SA2 ----------------
  fps_kernel<512, 128, 64><<<32, 64, 0, stream>>>(nx1_soa, 1536, 512, nx2_aos, nx2_soa);
  ballq_wave<512, 64, 128><<<32 * 128, 64, 0, stream>>>(nx1_soa, 1536, 512, nx2_aos, idx2, r2b);

  sa2_fused<<<4096, 256, 0, stream>>>(
      f1h, f1l, nx1_aos, nx2_aos, idx2,
      wph[3], wpl[3], sa2_b[0],
      wph[4], wpl[4], sa2_b[1],
      wph[5], wpl[5], sa2_b[2],
      f2h, f2l);

  // ---------------- loc MLP (fused global maxpool at L3) ----------------
  mfma_gemm<128, 0><<<dim3(2, 32), 256, 0, stream>>>(
      f2h, f2l, wph[6], wpl[6], loc_b[0], Yh, Yl, nullptr, nullptr, nullptr, 256, 256);
  mfma_gemm<128, 0><<<dim3(4, 32), 256, 0, stream>>>(
      Yh, Yl, wph[7], wpl[7], loc_b[1], Xh, Xl, nullptr, nullptr, nullptr, 256, 512);
  mfma_gemm<128, 128><<<dim3(8, 32), 256, 0, stream>>>(
      Xh, Xl, wph[8], wpl[8], loc_b[2], nullptr, nullptr, pooled, nullptr, nullptr, 512, 1024);

  // ---------------- fused head ----------------
  head_kernel<<<32, 256, 0, stream>>>(pooled, glob_w0, glob_b0,
                                      glob_w1, glob_b1, cls_w, cls_b, (float*)d_out);
}

// Round 12
// 1156.945 us; speedup vs baseline: 1.1160x; 1.1160x over previous
//
#include <hip/hip_runtime.h>
#include <hip/hip_bf16.h>
#include <cstdint>

#define CDIV(a,b) (((a)+(b)-1)/(b))

typedef short s8v __attribute__((ext_vector_type(8)));
typedef float f4v __attribute__((ext_vector_type(4)));
typedef float f2v __attribute__((ext_vector_type(2)));

// ---------------------------------------------------------------------
// helpers
// ---------------------------------------------------------------------
__device__ __forceinline__ unsigned short f2bf_bits(float v) {
  __hip_bfloat16 b = __float2bfloat16(v);
  unsigned short u; __builtin_memcpy(&u, &b, 2);
  return u;
}
__device__ __forceinline__ void bsplit(float v, unsigned short& h, unsigned short& l) {
  __hip_bfloat16 hb = __float2bfloat16(v);
  float hf = __bfloat162float(hb);
  unsigned short hu; __builtin_memcpy(&hu, &hb, 2);
  h = hu;
  l = f2bf_bits(v - hf);
}

// AGPR pin: store/reload a float in an accumulator register (unified RF).
__device__ __forceinline__ void agpr_put(float& slot, float v) {
  asm volatile("v_accvgpr_write_b32 %0, %1" : "=a"(slot) : "v"(v));
}
__device__ __forceinline__ float agpr_get(const float& slot) {
  float v;
  asm volatile("v_accvgpr_read_b32 %0, %1" : "=v"(v) : "a"(slot));
  return v;
}

// packed 2xfp32 VALU (VOP3P)
__device__ __forceinline__ f2v pk_add(f2v a, f2v b) {
  f2v d; asm("v_pk_add_f32 %0, %1, %2" : "=v"(d) : "v"(a), "v"(b)); return d;
}
__device__ __forceinline__ f2v pk_mul(f2v a, f2v b) {
  f2v d; asm("v_pk_mul_f32 %0, %1, %2" : "=v"(d) : "v"(a), "v"(b)); return d;
}
__device__ __forceinline__ f2v pk_fma(f2v a, f2v b, f2v c) {
  f2v d; asm("v_pk_fma_f32 %0, %1, %2, %3" : "=v"(d) : "v"(a), "v"(b), "v"(c)); return d;
}

// ---------------------------------------------------------------------
// FPS — coords AGPR-pinned, packed fp32 distance math, key-only DPP
// argmax. NTHR=512 is the measured optimum (R11: 1024 regressed — the
// combine chain is redundant per-wave; more waves only add issue).
// Fused centroid gather epilogue writes AoS+SoA directly from LDS.
// ---------------------------------------------------------------------
template<int C>
__device__ __forceinline__ unsigned dpp32(unsigned v) {
  return (unsigned)__builtin_amdgcn_update_dpp((int)v, (int)v, C, 0xF, 0xF, false);
}
template<int C>
__device__ __forceinline__ unsigned long long red_key(unsigned long long pk) {
  unsigned lo = dpp32<C>((unsigned)pk);
  unsigned hi = dpp32<C>((unsigned)(pk >> 32));
  unsigned long long p2 = ((unsigned long long)hi << 32) | lo;
  return (p2 > pk) ? p2 : pk;
}

template<int NPTS, int MOUT, int NTHR>
__global__ __launch_bounds__(NTHR, 1) void fps_kernel(
    const float* __restrict__ pts, int bstride, int cstride,
    float* __restrict__ aos, float* __restrict__ soa)
{
  constexpr int PPT = NPTS / NTHR;   // must be even
  constexpr int NP2 = PPT / 2;
  constexpr int NW  = NTHR / 64;
  const int b = blockIdx.x, t = threadIdx.x;
  const int lane = t & 63;
  const int wid = t >> 6;
  const float* px = pts + (size_t)b * bstride;
  const float* py = px + cstride;
  const float* pz = px + 2 * cstride;
  __shared__ float s_x[NPTS], s_y[NPTS], s_z[NPTS];
  __shared__ unsigned long long s_key[2][NW > 1 ? NW : 1];
  __shared__ int s_out[MOUT];

  float ax[PPT], ay[PPT], az[PPT];   // AGPR-resident
  f2v dsv[NP2];                      // VGPR-resident (mutated)
#pragma unroll
  for (int j = 0; j < PPT; ++j) {
    int i = t + j * NTHR;
    float x = px[i], y = py[i], z = pz[i];
    s_x[i] = x; s_y[i] = y; s_z[i] = z;
    agpr_put(ax[j], x); agpr_put(ay[j], y); agpr_put(az[j], z);
  }
#pragma unroll
  for (int q = 0; q < NP2; ++q) dsv[q] = (f2v){1e10f, 1e10f};
  if (t == 0) s_out[0] = 0;
  float lx = px[0], ly = py[0], lz = pz[0];
  __syncthreads();

  for (int it = 1; it < MOUT; ++it) {
    const f2v nlx = (f2v){-lx, -lx};
    const f2v nly = (f2v){-ly, -ly};
    const f2v nlz = (f2v){-lz, -lz};
    float bestv = -1.0f; int bestj = 0;
#pragma unroll
    for (int q = 0; q < NP2; ++q) {
      f2v x2, y2, z2;
      x2.x = agpr_get(ax[2 * q]); x2.y = agpr_get(ax[2 * q + 1]);
      y2.x = agpr_get(ay[2 * q]); y2.y = agpr_get(ay[2 * q + 1]);
      z2.x = agpr_get(az[2 * q]); z2.y = agpr_get(az[2 * q + 1]);
      f2v dx = pk_add(x2, nlx);
      f2v dy = pk_add(y2, nly);
      f2v dz = pk_add(z2, nlz);
      f2v d2 = pk_fma(dz, dz, pk_fma(dy, dy, pk_mul(dx, dx)));
      float nd0 = fminf(dsv[q].x, d2.x);
      float nd1 = fminf(dsv[q].y, d2.y);
      dsv[q].x = nd0; dsv[q].y = nd1;
      if (nd0 > bestv) { bestv = nd0; bestj = 2 * q; }
      if (nd1 > bestv) { bestv = nd1; bestj = 2 * q + 1; }
    }
    const int besti = t + bestj * NTHR;   // global point index (NTHR-invariant key)
    unsigned long long pk =
        ((unsigned long long)__float_as_uint(bestv) << 32) | (unsigned)(~(unsigned)besti);
    pk = red_key<0x111>(pk);
    pk = red_key<0x112>(pk);
    pk = red_key<0x114>(pk);
    pk = red_key<0x118>(pk);
    pk = red_key<0x142>(pk);
    pk = red_key<0x143>(pk);
    int widx;
    if constexpr (NW == 1) {
      widx = (int)(~(unsigned)__builtin_amdgcn_readlane((int)(unsigned)pk, 63));
    } else {
      const int pb = it & 1;
      if (lane == 63) s_key[pb][wid] = pk;
      __syncthreads();
      unsigned long long ck = s_key[pb][lane & (NW - 1)];
      if (NW >= 2)  ck = red_key<0x111>(ck);
      if (NW >= 4)  ck = red_key<0x112>(ck);
      if (NW >= 8)  ck = red_key<0x114>(ck);
      if (NW >= 16) ck = red_key<0x118>(ck);
      widx = (int)(~(unsigned)__builtin_amdgcn_readlane((int)(unsigned)ck, NW - 1));
    }
    lx = s_x[widx]; ly = s_y[widx]; lz = s_z[widx];
    if (t == 0) s_out[it] = widx;
  }
  __syncthreads();
  // fused centroid gather: AoS + SoA straight from LDS
  for (int i = t; i < MOUT; i += NTHR) {
    const int idx = s_out[i];
    const float x = s_x[idx], y = s_y[idx], z = s_z[idx];
    float* a = aos + ((size_t)b * MOUT + i) * 3;
    a[0] = x; a[1] = y; a[2] = z;
    soa[(size_t)b * 3 * MOUT + i]            = x;
    soa[(size_t)b * 3 * MOUT + MOUT + i]     = y;
    soa[(size_t)b * 3 * MOUT + 2 * MOUT + i] = z;
  }
}

// ---------------- ball query — one wave per centroid ------------------
// 2 points per lane per chunk (128-pt chunks): halves the serial
// ballot->base dependency chain. First-k index order preserved
// (sub-chunk 0 ranked before sub-chunk 1).
template<int NPTS, int KNB, int MC>
__global__ __launch_bounds__(64) void ballq_wave(
    const float* __restrict__ pts, int bstride, int cstride,
    const float* __restrict__ cents, int* __restrict__ out, float r2)
{
  constexpr int NCH = NPTS / 128;
  const int g = blockIdx.x;
  const int b = g / MC;
  const int lane = threadIdx.x;
  const float* px = pts + (size_t)b * bstride;
  const float* py = px + cstride;
  const float* pz = px + 2 * cstride;
  const float cx = cents[g * 3 + 0], cy = cents[g * 3 + 1], cz = cents[g * 3 + 2];
  __shared__ int s_idx[KNB];
  float ax0 = px[lane],      ay0 = py[lane],      az0 = pz[lane];
  float ax1 = px[64 + lane], ay1 = py[64 + lane], az1 = pz[64 + lane];
  int base = 0;
  const unsigned long long below = (1ull << lane) - 1ull;
  for (int c = 0; c < NCH; ++c) {
    float X0 = ax0, Y0 = ay0, Z0 = az0;
    float X1 = ax1, Y1 = ay1, Z1 = az1;
    if (c + 1 < NCH) {
      int i0 = (c + 1) * 128 + lane;
      ax0 = px[i0];      ay0 = py[i0];      az0 = pz[i0];
      ax1 = px[i0 + 64]; ay1 = py[i0 + 64]; az1 = pz[i0 + 64];
    }
    float dx0 = X0 - cx, dy0 = Y0 - cy, dz0 = Z0 - cz;
    float dx1 = X1 - cx, dy1 = Y1 - cy, dz1 = Z1 - cz;
    bool v0 = (dx0 * dx0 + dy0 * dy0 + dz0 * dz0) < r2;
    bool v1 = (dx1 * dx1 + dy1 * dy1 + dz1 * dz1) < r2;
    unsigned long long m0 = __ballot(v0);
    unsigned long long m1 = __ballot(v1);
    int r0 = __popcll(m0 & below);
    int p0 = base + r0;
    if (v0 && p0 < KNB) s_idx[p0] = c * 128 + lane;
    int base1 = base + __popcll(m0);
    int r1 = __popcll(m1 & below);
    int p1 = base1 + r1;
    if (v1 && p1 < KNB) s_idx[p1] = c * 128 + 64 + lane;
    base = base1 + __popcll(m1);
    if (base >= KNB) break;   // wave-uniform
  }
  int total = base < KNB ? base : KNB;   // >=1 (centroid hits itself)
  int first = s_idx[0];
  if (lane < KNB)
    out[(size_t)g * KNB + lane] = (lane < total) ? s_idx[lane] : first;
}

// ---------------------------------------------------------------------
// Embedded FPS stage 2 (512 pts -> 128), 256 threads, PPT=2, NW=4.
// Runs in sa1_fused's leading 32 blocks, overlapped with SA1 compute.
// Selection identical to any NTHR variant (keys use global indices).
// ---------------------------------------------------------------------
__device__ void fps2_embed(
    const float* __restrict__ soa_in, int b,
    float* __restrict__ aos, float* __restrict__ soa,
    float* fx, float* fy, float* fz, int* fout,
    unsigned long long* fkey /* [2][4] */, int t)
{
  const int lane = t & 63, wid = t >> 6;
  const float* px = soa_in + (size_t)b * 1536;
  const float* py = px + 512;
  const float* pz = px + 1024;
  float x0, y0, z0, x1, y1, z1;
  {
    const int i0 = t, i1 = t + 256;
    x0 = px[i0]; y0 = py[i0]; z0 = pz[i0];
    x1 = px[i1]; y1 = py[i1]; z1 = pz[i1];
    fx[i0] = x0; fy[i0] = y0; fz[i0] = z0;
    fx[i1] = x1; fy[i1] = y1; fz[i1] = z1;
  }
  f2v ds = (f2v){1e10f, 1e10f};
  if (t == 0) fout[0] = 0;
  float lx = px[0], ly = py[0], lz = pz[0];
  __syncthreads();
  for (int it = 1; it < 128; ++it) {
    f2v X = (f2v){x0, x1}, Y = (f2v){y0, y1}, Z = (f2v){z0, z1};
    f2v dx = pk_add(X, (f2v){-lx, -lx});
    f2v dy = pk_add(Y, (f2v){-ly, -ly});
    f2v dz = pk_add(Z, (f2v){-lz, -lz});
    f2v d2 = pk_fma(dz, dz, pk_fma(dy, dy, pk_mul(dx, dx)));
    float nd0 = fminf(ds.x, d2.x);
    float nd1 = fminf(ds.y, d2.y);
    ds.x = nd0; ds.y = nd1;
    float bestv = nd0; int bestj = 0;
    if (nd1 > bestv) { bestv = nd1; bestj = 1; }
    const int besti = t + bestj * 256;
    unsigned long long pk =
        ((unsigned long long)__float_as_uint(bestv) << 32) | (unsigned)(~(unsigned)besti);
    pk = red_key<0x111>(pk);
    pk = red_key<0x112>(pk);
    pk = red_key<0x114>(pk);
    pk = red_key<0x118>(pk);
    pk = red_key<0x142>(pk);
    pk = red_key<0x143>(pk);
    const int pb = it & 1;
    if (lane == 63) fkey[pb * 4 + wid] = pk;
    __syncthreads();
    unsigned long long ck = fkey[pb * 4 + (lane & 3)];
    ck = red_key<0x111>(ck);
    ck = red_key<0x112>(ck);
    const int widx = (int)(~(unsigned)__builtin_amdgcn_readlane((int)(unsigned)ck, 3));
    lx = fx[widx]; ly = fy[widx]; lz = fz[widx];
    if (t == 0) fout[it] = widx;
  }
  __syncthreads();
  if (t < 128) {
    const int idx = fout[t];
    const float x = fx[idx], y = fy[idx], z = fz[idx];
    float* a = aos + ((size_t)b * 128 + t) * 3;
    a[0] = x; a[1] = y; a[2] = z;
    soa[(size_t)b * 384 + t]       = x;
    soa[(size_t)b * 384 + 128 + t] = y;
    soa[(size_t)b * 384 + 256 + t] = z;
  }
}

// ---------------------------------------------------------------------
// SA1 fully fused + 32 leading fps2 blocks (grid = 32 + 4096).
// ---------------------------------------------------------------------
__global__ __launch_bounds__(256, 1) void sa1_fused(
    const float* __restrict__ pts, const int* __restrict__ idx1,
    const float* __restrict__ cents,
    const float* __restrict__ w0, const float* __restrict__ b0,
    const unsigned short* __restrict__ w1h, const unsigned short* __restrict__ w1l,
    const float* __restrict__ b1,
    const unsigned short* __restrict__ w2h, const unsigned short* __restrict__ w2l,
    const float* __restrict__ b2,
    unsigned short* __restrict__ f1h, unsigned short* __restrict__ f1l,
    const float* __restrict__ nx1_soa, float* __restrict__ nx2_aos,
    float* __restrict__ nx2_soa)
{
  __shared__ __align__(16) unsigned short sY[2][128 * 72];
  __shared__ __align__(16) unsigned short sZ[2][128 * 72];
  __shared__ __align__(16) unsigned short sW[2][64 * 72];
  __shared__ float sw0[192];
  __shared__ float sb0[64];

  const int tid = threadIdx.x, lane = tid & 63, wid = tid >> 6;
  const int wm = wid & 1, wn = wid >> 1;
  const int mn15 = lane & 15, kgrp = lane >> 4;

  if (blockIdx.x < 32) {
    // ---- embedded fps2, LDS scratch overlays sY ----
    float* fx = (float*)&sY[0][0];
    float* fy = fx + 512;
    float* fz = fy + 512;
    int*   fout = (int*)(fz + 512);
    unsigned long long* fkey = (unsigned long long*)(fout + 128);
    fps2_embed(nx1_soa, blockIdx.x, nx2_aos, nx2_soa, fx, fy, fz, fout, fkey, tid);
    return;
  }
  const int bk = blockIdx.x - 32;

  if (tid < 192) sw0[tid] = w0[tid];
  else sb0[tid - 192] = b0[tid - 192];
  for (int gi = tid; gi < 1024; gi += 256) {
    const int pl = gi >> 9, idx = gi & 511;
    const int n = idx >> 3, k8 = idx & 7;
    const uint4 v = ((const uint4*)(pl ? w1l : w1h))[idx];
    *(uint4*)&sW[pl][n * 72 + k8 * 8] = v;
  }
  __syncthreads();

  {
    const int rl = tid >> 1, half = tid & 1;
    const int r = bk * 128 + rl;
    const int gl = r >> 5, j = r & 31, b = gl >> 9;
    const int i = idx1[(size_t)gl * 32 + j];
    const float* px = pts + (size_t)b * 24576;
    const float x = px[i]         - cents[gl * 3 + 0];
    const float y = px[8192 + i]  - cents[gl * 3 + 1];
    const float z = px[16384 + i] - cents[gl * 3 + 2];
    union { unsigned short us[32]; uint4 v[4]; } ph, pl4;
#pragma unroll
    for (int u = 0; u < 32; ++u) {
      const int o = half * 32 + u;
      float v = sw0[o * 3] * x + sw0[o * 3 + 1] * y + sw0[o * 3 + 2] * z + sb0[o];
      v = fmaxf(v, 0.f);
      bsplit(v, ph.us[u], pl4.us[u]);
    }
    const int base = rl * 72 + half * 32;
#pragma unroll
    for (int g = 0; g < 4; ++g) {
      *(uint4*)&sY[0][base + g * 8] = ph.v[g];
      *(uint4*)&sY[1][base + g * 8] = pl4.v[g];
    }
  }
  __syncthreads();

  {
    f4v acc[4][2];
#pragma unroll
    for (int a = 0; a < 4; ++a)
#pragma unroll
      for (int c = 0; c < 2; ++c) acc[a][c] = (f4v){0.f, 0.f, 0.f, 0.f};
#pragma unroll
    for (int kc = 0; kc < 2; ++kc) {
      const int k0 = kc * 32;
      s8v af[2][4], bf[2][2];
#pragma unroll
      for (int mt = 0; mt < 4; ++mt) {
        const int m = wm * 64 + mt * 16 + mn15;
        af[0][mt] = *(const s8v*)&sY[0][m * 72 + k0 + kgrp * 8];
        af[1][mt] = *(const s8v*)&sY[1][m * 72 + k0 + kgrp * 8];
      }
#pragma unroll
      for (int nt = 0; nt < 2; ++nt) {
        const int n = wn * 32 + nt * 16 + mn15;
        bf[0][nt] = *(const s8v*)&sW[0][n * 72 + k0 + kgrp * 8];
        bf[1][nt] = *(const s8v*)&sW[1][n * 72 + k0 + kgrp * 8];
      }
#pragma unroll
      for (int mt = 0; mt < 4; ++mt)
#pragma unroll
        for (int nt = 0; nt < 2; ++nt) {
          acc[mt][nt] = __builtin_amdgcn_mfma_f32_16x16x32_bf16(af[0][mt], bf[0][nt], acc[mt][nt], 0, 0, 0);
          acc[mt][nt] = __builtin_amdgcn_mfma_f32_16x16x32_bf16(af[0][mt], bf[1][nt], acc[mt][nt], 0, 0, 0);
          acc[mt][nt] = __builtin_amdgcn_mfma_f32_16x16x32_bf16(af[1][mt], bf[0][nt], acc[mt][nt], 0, 0, 0);
        }
    }
#pragma unroll
    for (int nt = 0; nt < 2; ++nt) {
      const int n = wn * 32 + nt * 16 + mn15;
      const float bv = b1[n];
#pragma unroll
      for (int mt = 0; mt < 4; ++mt)
#pragma unroll
        for (int r = 0; r < 4; ++r) {
          const int m = wm * 64 + mt * 16 + (lane >> 4) * 4 + r;
          float v = fmaxf(acc[mt][nt][r] + bv, 0.f);
          unsigned short h, l; bsplit(v, h, l);
          sZ[0][m * 72 + n] = h;
          sZ[1][m * 72 + n] = l;
        }
    }
  }
  __syncthreads();

  for (int gi = tid; gi < 2048; gi += 256) {
    const int pl = gi >> 10, idx = gi & 1023;
    const int n = idx >> 3, k8 = idx & 7;
    const uint4 v = ((const uint4*)(pl ? w2l : w2h))[idx];
    *(uint4*)&sY[pl][n * 72 + k8 * 8] = v;
  }
  __syncthreads();

  {
    f4v acc[4][4];
#pragma unroll
    for (int a = 0; a < 4; ++a)
#pragma unroll
      for (int c = 0; c < 4; ++c) acc[a][c] = (f4v){0.f, 0.f, 0.f, 0.f};
#pragma unroll
    for (int kc = 0; kc < 2; ++kc) {
      const int k0 = kc * 32;
      s8v af[2][4], bf[2][4];
#pragma unroll
      for (int mt = 0; mt < 4; ++mt) {
        const int m = wm * 64 + mt * 16 + mn15;
        af[0][mt] = *(const s8v*)&sZ[0][m * 72 + k0 + kgrp * 8];
        af[1][mt] = *(const s8v*)&sZ[1][m * 72 + k0 + kgrp * 8];
      }
#pragma unroll
      for (int nt = 0; nt < 4; ++nt) {
        const int n = wn * 64 + nt * 16 + mn15;
        bf[0][nt] = *(const s8v*)&sY[0][n * 72 + k0 + kgrp * 8];
        bf[1][nt] = *(const s8v*)&sY[1][n * 72 + k0 + kgrp * 8];
      }
#pragma unroll
      for (int mt = 0; mt < 4; ++mt)
#pragma unroll
        for (int nt = 0; nt < 4; ++nt) {
          acc[mt][nt] = __builtin_amdgcn_mfma_f32_16x16x32_bf16(af[0][mt], bf[0][nt], acc[mt][nt], 0, 0, 0);
          acc[mt][nt] = __builtin_amdgcn_mfma_f32_16x16x32_bf16(af[0][mt], bf[1][nt], acc[mt][nt], 0, 0, 0);
          acc[mt][nt] = __builtin_amdgcn_mfma_f32_16x16x32_bf16(af[1][mt], bf[0][nt], acc[mt][nt], 0, 0, 0);
        }
    }
#pragma unroll
    for (int gq = 0; gq < 2; ++gq)
#pragma unroll
      for (int nt = 0; nt < 4; ++nt) {
        const int n = wn * 64 + nt * 16 + mn15;
        float v = -1e30f;
#pragma unroll
        for (int mt = 2 * gq; mt < 2 * gq + 2; ++mt)
#pragma unroll
          for (int r = 0; r < 4; ++r) v = fmaxf(v, acc[mt][nt][r]);
        v = fmaxf(v + b2[n], 0.f);
        v = fmaxf(v, __shfl_xor(v, 16, 64));
        v = fmaxf(v, __shfl_xor(v, 32, 64));
        if (lane < 16) {
          const size_t row = (size_t)bk * 4 + wm * 2 + gq;
          unsigned short h, l; bsplit(v, h, l);
          f1h[row * 128 + n] = h;
          f1l[row * 128 + n] = l;
        }
      }
  }
}

// ---------------------------------------------------------------------
// SA2 fully fused (unchanged from R10)
// ---------------------------------------------------------------------
__global__ __launch_bounds__(256, 1) void sa2_fused(
    const unsigned short* __restrict__ f1h, const unsigned short* __restrict__ f1l,
    const float* __restrict__ nx1_aos, const float* __restrict__ nx2_aos,
    const int* __restrict__ idx2,
    const unsigned short* __restrict__ w1h, const unsigned short* __restrict__ w1l,
    const float* __restrict__ b1,
    const unsigned short* __restrict__ w2h, const unsigned short* __restrict__ w2l,
    const float* __restrict__ b2,
    const unsigned short* __restrict__ w3h, const unsigned short* __restrict__ w3l,
    const float* __restrict__ b3,
    unsigned short* __restrict__ f2h, unsigned short* __restrict__ f2l)
{
  __shared__ __align__(16) unsigned short sX[2][64 * 160];  // X; later Z (stride 136)
  __shared__ __align__(16) unsigned short sY[2][64 * 136];
  __shared__ __align__(16) unsigned short sW[4][2][32 * 40]; // per-wave W regions

  const int tid = threadIdx.x, lane = tid & 63, wid = tid >> 6;
  const int mn15 = lane & 15, kgrp = lane >> 4;
  const int gg = blockIdx.x;
  const int bb = gg >> 7;

  {
    const int r = tid >> 2, q = tid & 3;
    const int i = idx2[(size_t)gg * 64 + r];
    const int p = bb * 512 + i;
#pragma unroll
    for (int pl = 0; pl < 2; ++pl) {
      const uint4* src = (const uint4*)((pl ? f1l : f1h) + (size_t)p * 128);
#pragma unroll
      for (int g = 0; g < 4; ++g)
        *(uint4*)&sX[pl][r * 160 + (q * 4 + g) * 8] = src[q * 4 + g];
    }
    if (q == 0) {
      union { unsigned short us[8]; uint4 v; } ph, pl4;
#pragma unroll
      for (int u = 0; u < 8; ++u) { ph.us[u] = 0; pl4.us[u] = 0; }
#pragma unroll
      for (int c = 0; c < 3; ++c) {
        float v = nx1_aos[(size_t)p * 3 + c] - nx2_aos[(size_t)gg * 3 + c];
        bsplit(v, ph.us[c], pl4.us[c]);
      }
      *(uint4*)&sX[0][r * 160 + 128] = ph.v;
      *(uint4*)&sX[1][r * 160 + 128] = pl4.v;
    } else {
      uint4 z = make_uint4(0, 0, 0, 0);
      *(uint4*)&sX[0][r * 160 + 128 + q * 8] = z;
      *(uint4*)&sX[1][r * 160 + 128 + q * 8] = z;
    }
  }
  __syncthreads();

  const int spl = lane >> 5, srow = lane & 31;
  unsigned short* swb = &sW[wid][0][0];

  // ============ L1: 64x128, K=160 (5 chunks) ============
  {
    f4v acc[4][2];
#pragma unroll
    for (int a = 0; a < 4; ++a)
#pragma unroll
      for (int c = 0; c < 2; ++c) acc[a][c] = (f4v){0.f, 0.f, 0.f, 0.f};
    uint4 pf[4];
    {
      const unsigned short* s = (spl ? w1l : w1h) + (size_t)(wid * 32 + srow) * 160;
#pragma unroll
      for (int g = 0; g < 4; ++g) pf[g] = *(const uint4*)(s + g * 8);
    }
#pragma unroll
    for (int c = 0; c < 5; ++c) {
      unsigned short* d = swb + spl * 1280 + srow * 40;
#pragma unroll
      for (int g = 0; g < 4; ++g) *(uint4*)(d + g * 8) = pf[g];
      if (c < 4) {
        const unsigned short* s = (spl ? w1l : w1h) + (size_t)(wid * 32 + srow) * 160 + (c + 1) * 32;
#pragma unroll
        for (int g = 0; g < 4; ++g) pf[g] = *(const uint4*)(s + g * 8);
      }
      const int k0 = c * 32;
      s8v af[2][4], bf[2][2];
#pragma unroll
      for (int mt = 0; mt < 4; ++mt) {
        const int m = mt * 16 + mn15;
        af[0][mt] = *(const s8v*)&sX[0][m * 160 + k0 + kgrp * 8];
        af[1][mt] = *(const s8v*)&sX[1][m * 160 + k0 + kgrp * 8];
      }
#pragma unroll
      for (int nt = 0; nt < 2; ++nt) {
        const int nl = nt * 16 + mn15;
        bf[0][nt] = *(const s8v*)&swb[0 * 1280 + nl * 40 + kgrp * 8];
        bf[1][nt] = *(const s8v*)&swb[1 * 1280 + nl * 40 + kgrp * 8];
      }
#pragma unroll
      for (int mt = 0; mt < 4; ++mt)
#pragma unroll
        for (int nt = 0; nt < 2; ++nt) {
          acc[mt][nt] = __builtin_amdgcn_mfma_f32_16x16x32_bf16(af[0][mt], bf[0][nt], acc[mt][nt], 0, 0, 0);
          acc[mt][nt] = __builtin_amdgcn_mfma_f32_16x16x32_bf16(af[0][mt], bf[1][nt], acc[mt][nt], 0, 0, 0);
          acc[mt][nt] = __builtin_amdgcn_mfma_f32_16x16x32_bf16(af[1][mt], bf[0][nt], acc[mt][nt], 0, 0, 0);
        }
    }
#pragma unroll
    for (int nt = 0; nt < 2; ++nt) {
      const int n = wid * 32 + nt * 16 + mn15;
      const float bv = b1[n];
#pragma unroll
      for (int mt = 0; mt < 4; ++mt)
#pragma unroll
        for (int r = 0; r < 4; ++r) {
          const int m = mt * 16 + kgrp * 4 + r;
          float v = fmaxf(acc[mt][nt][r] + bv, 0.f);
          unsigned short h, l; bsplit(v, h, l);
          sY[0][m * 136 + n] = h;
          sY[1][m * 136 + n] = l;
        }
    }
  }
  __syncthreads();

  // ============ L2: 64x128, K=128 (4 chunks), out -> Z (overlay sX) ===
  {
    f4v acc[4][2];
#pragma unroll
    for (int a = 0; a < 4; ++a)
#pragma unroll
      for (int c = 0; c < 2; ++c) acc[a][c] = (f4v){0.f, 0.f, 0.f, 0.f};
    uint4 pf[4];
    {
      const unsigned short* s = (spl ? w2l : w2h) + (size_t)(wid * 32 + srow) * 128;
#pragma unroll
      for (int g = 0; g < 4; ++g) pf[g] = *(const uint4*)(s + g * 8);
    }
#pragma unroll
    for (int c = 0; c < 4; ++c) {
      unsigned short* d = swb + spl * 1280 + srow * 40;
#pragma unroll
      for (int g = 0; g < 4; ++g) *(uint4*)(d + g * 8) = pf[g];
      if (c < 3) {
        const unsigned short* s = (spl ? w2l : w2h) + (size_t)(wid * 32 + srow) * 128 + (c + 1) * 32;
#pragma unroll
        for (int g = 0; g < 4; ++g) pf[g] = *(const uint4*)(s + g * 8);
      }
      const int k0 = c * 32;
      s8v af[2][4], bf[2][2];
#pragma unroll
      for (int mt = 0; mt < 4; ++mt) {
        const int m = mt * 16 + mn15;
        af[0][mt] = *(const s8v*)&sY[0][m * 136 + k0 + kgrp * 8];
        af[1][mt] = *(const s8v*)&sY[1][m * 136 + k0 + kgrp * 8];
      }
#pragma unroll
      for (int nt = 0; nt < 2; ++nt) {
        const int nl = nt * 16 + mn15;
        bf[0][nt] = *(const s8v*)&swb[0 * 1280 + nl * 40 + kgrp * 8];
        bf[1][nt] = *(const s8v*)&swb[1 * 1280 + nl * 40 + kgrp * 8];
      }
#pragma unroll
      for (int mt = 0; mt < 4; ++mt)
#pragma unroll
        for (int nt = 0; nt < 2; ++nt) {
          acc[mt][nt] = __builtin_amdgcn_mfma_f32_16x16x32_bf16(af[0][mt], bf[0][nt], acc[mt][nt], 0, 0, 0);
          acc[mt][nt] = __builtin_amdgcn_mfma_f32_16x16x32_bf16(af[0][mt], bf[1][nt], acc[mt][nt], 0, 0, 0);
          acc[mt][nt] = __builtin_amdgcn_mfma_f32_16x16x32_bf16(af[1][mt], bf[0][nt], acc[mt][nt], 0, 0, 0);
        }
    }
#pragma unroll
    for (int nt = 0; nt < 2; ++nt) {
      const int n = wid * 32 + nt * 16 + mn15;
      const float bv = b2[n];
#pragma unroll
      for (int mt = 0; mt < 4; ++mt)
#pragma unroll
        for (int r = 0; r < 4; ++r) {
          const int m = mt * 16 + kgrp * 4 + r;
          float v = fmaxf(acc[mt][nt][r] + bv, 0.f);
          unsigned short h, l; bsplit(v, h, l);
          sX[0][m * 136 + n] = h;
          sX[1][m * 136 + n] = l;
        }
    }
  }
  __syncthreads();

  // ============ L3: 64x256, K=128, two 32-col halves + pool-64 ========
#pragma unroll
  for (int h = 0; h < 2; ++h) {
    f4v acc[4][2];
#pragma unroll
    for (int a = 0; a < 4; ++a)
#pragma unroll
      for (int c = 0; c < 2; ++c) acc[a][c] = (f4v){0.f, 0.f, 0.f, 0.f};
    const int nb = wid * 64 + h * 32;
    uint4 pf[4];
    {
      const unsigned short* s = (spl ? w3l : w3h) + (size_t)(nb + srow) * 128;
#pragma unroll
      for (int g = 0; g < 4; ++g) pf[g] = *(const uint4*)(s + g * 8);
    }
#pragma unroll
    for (int c = 0; c < 4; ++c) {
      unsigned short* d = swb + spl * 1280 + srow * 40;
#pragma unroll
      for (int g = 0; g < 4; ++g) *(uint4*)(d + g * 8) = pf[g];
      if (c < 3) {
        const unsigned short* s = (spl ? w3l : w3h) + (size_t)(nb + srow) * 128 + (c + 1) * 32;
#pragma unroll
        for (int g = 0; g < 4; ++g) pf[g] = *(const uint4*)(s + g * 8);
      }
      const int k0 = c * 32;
      s8v af[2][4], bf[2][2];
#pragma unroll
      for (int mt = 0; mt < 4; ++mt) {
        const int m = mt * 16 + mn15;
        af[0][mt] = *(const s8v*)&sX[0][m * 136 + k0 + kgrp * 8];
        af[1][mt] = *(const s8v*)&sX[1][m * 136 + k0 + kgrp * 8];
      }
#pragma unroll
      for (int nt = 0; nt < 2; ++nt) {
        const int nl = nt * 16 + mn15;
        bf[0][nt] = *(const s8v*)&swb[0 * 1280 + nl * 40 + kgrp * 8];
        bf[1][nt] = *(const s8v*)&swb[1 * 1280 + nl * 40 + kgrp * 8];
      }
#pragma unroll
      for (int mt = 0; mt < 4; ++mt)
#pragma unroll
        for (int nt = 0; nt < 2; ++nt) {
          acc[mt][nt] = __builtin_amdgcn_mfma_f32_16x16x32_bf16(af[0][mt], bf[0][nt], acc[mt][nt], 0, 0, 0);
          acc[mt][nt] = __builtin_amdgcn_mfma_f32_16x16x32_bf16(af[0][mt], bf[1][nt], acc[mt][nt], 0, 0, 0);
          acc[mt][nt] = __builtin_amdgcn_mfma_f32_16x16x32_bf16(af[1][mt], bf[0][nt], acc[mt][nt], 0, 0, 0);
        }
    }
#pragma unroll
    for (int nt = 0; nt < 2; ++nt) {
      const int n = nb + nt * 16 + mn15;
      float v = -1e30f;
#pragma unroll
      for (int mt = 0; mt < 4; ++mt)
#pragma unroll
        for (int r = 0; r < 4; ++r) v = fmaxf(v, acc[mt][nt][r]);
      v = fmaxf(v + b3[n], 0.f);
      v = fmaxf(v, __shfl_xor(v, 16, 64));
      v = fmaxf(v, __shfl_xor(v, 32, 64));
      if (lane < 16) {
        unsigned short hh, ll; bsplit(v, hh, ll);
        f2h[(size_t)gg * 256 + n] = hh;
        f2l[(size_t)gg * 256 + n] = ll;
      }
    }
  }
}

// ------------- all weight fp32 -> hi/lo splits in ONE launch -----------
struct WSplitArgs {
  const float* src[9];
  unsigned short* h[9];
  unsigned short* l[9];
  int K[9];
  int KP[9];
  int perm[9];
  int cum[10];
};
__global__ void wsplit_all(WSplitArgs a) {
  int i = blockIdx.x * 256 + threadIdx.x;
  if (i >= a.cum[9]) return;
  int s = 0;
#pragma unroll
  for (int t = 1; t < 9; ++t) s += (i >= a.cum[t]);
  int local = i - a.cum[s];
  int KP = a.KP[s], K = a.K[s];
  int r = local / KP, k = local - r * KP;
  int oc;
  if (a.perm[s]) oc = (k < 128) ? k + 3 : (k < 131 ? k - 128 : -1);
  else           oc = (k < K) ? k : -1;
  float v = (oc >= 0) ? a.src[s][(size_t)r * K + oc] : 0.f;
  unsigned short hb, lb; bsplit(v, hb, lb);
  a.h[s][local] = hb; a.l[s][local] = lb;
}

// ---------------------------------------------------------------------
// MFMA GEMM (loc MLP only)
// ---------------------------------------------------------------------
__device__ __forceinline__ void gl2lds16(const void* g, void* l, int lane) {
#if __has_builtin(__builtin_amdgcn_global_load_lds)
  __builtin_amdgcn_global_load_lds(
      (const __attribute__((address_space(1))) unsigned int*)g,
      (__attribute__((address_space(3))) unsigned int*)l, 16, 0, 0);
#else
  ((uint4*)l)[lane] = *(const uint4*)g;
#endif
}

template<int BN, int POOL>
__global__ __launch_bounds__(256, 1) void mfma_gemm(
    const unsigned short* __restrict__ Ah, const unsigned short* __restrict__ Al,
    const unsigned short* __restrict__ Wh, const unsigned short* __restrict__ Wl,
    const float* __restrict__ bias,
    unsigned short* __restrict__ Ch, unsigned short* __restrict__ Cl,
    float* __restrict__ Cf,
    int Kdim, int Ndim)
{
  constexpr int WTN = BN / 2, NT = WTN / 16;
  __shared__ unsigned short sA[2][128 * 32];
  __shared__ unsigned short sW[2][BN * 32];
  __shared__ float sPool[4][WTN];
  const int tid = threadIdx.x, lane = tid & 63, wid = tid >> 6;
  const int wm = wid & 1, wn = wid >> 1;
  const size_t bm0 = (size_t)blockIdx.y * 128;
  const int bn0 = blockIdx.x * BN;
  const int mn15 = lane & 15, kgrp = lane >> 4;

  f4v acc[4][NT];
#pragma unroll
  for (int a = 0; a < 4; ++a)
#pragma unroll
    for (int b = 0; b < NT; ++b) acc[a][b] = (f4v){0.f, 0.f, 0.f, 0.f};

  const int sc = lane & 3, srl = lane >> 2;

  for (int k0 = 0; k0 < Kdim; k0 += 32) {
#pragma unroll
    for (int hh = 0; hh < 2; ++hh) {
      const int R = wid * 32 + hh * 16;
      const int m = R + srl;
      const int kg = (sc - m - (m >> 2)) & 3;
      const size_t go = (bm0 + m) * (size_t)Kdim + k0 + kg * 8;
      gl2lds16(Ah + go, &sA[0][R * 32], lane);
      gl2lds16(Al + go, &sA[1][R * 32], lane);
    }
#pragma unroll
    for (int hh = 0; hh < 2; ++hh) {
      const int R = wid * 32 + hh * 16;
      const int n = R + srl;
      const int kg = (sc - n - (n >> 2)) & 3;
      const size_t go = (size_t)(bn0 + n) * Kdim + k0 + kg * 8;
      gl2lds16(Wh + go, &sW[0][R * 32], lane);
      gl2lds16(Wl + go, &sW[1][R * 32], lane);
    }
    __syncthreads();

    s8v af[2][4], bfr[2][NT];
#pragma unroll
    for (int mt = 0; mt < 4; ++mt) {
      const int m = wm * 64 + mt * 16 + mn15;
      const int cc = (kgrp + m + (m >> 2)) & 3;
      af[0][mt] = *(const s8v*)&sA[0][m * 32 + cc * 8];
      af[1][mt] = *(const s8v*)&sA[1][m * 32 + cc * 8];
    }
#pragma unroll
    for (int nt = 0; nt < NT; ++nt) {
      const int n = wn * WTN + nt * 16 + mn15;
      const int cc = (kgrp + n + (n >> 2)) & 3;
      bfr[0][nt] = *(const s8v*)&sW[0][n * 32 + cc * 8];
      bfr[1][nt] = *(const s8v*)&sW[1][n * 32 + cc * 8];
    }
#pragma unroll
    for (int mt = 0; mt < 4; ++mt)
#pragma unroll
      for (int nt = 0; nt < NT; ++nt) {
        acc[mt][nt] = __builtin_amdgcn_mfma_f32_16x16x32_bf16(af[0][mt], bfr[0][nt], acc[mt][nt], 0, 0, 0);
        acc[mt][nt] = __builtin_amdgcn_mfma_f32_16x16x32_bf16(af[0][mt], bfr[1][nt], acc[mt][nt], 0, 0, 0);
        acc[mt][nt] = __builtin_amdgcn_mfma_f32_16x16x32_bf16(af[1][mt], bfr[0][nt], acc[mt][nt], 0, 0, 0);
      }
    __syncthreads();
  }

  float bv[NT];
#pragma unroll
  for (int nt = 0; nt < NT; ++nt) bv[nt] = bias[bn0 + wn * WTN + nt * 16 + mn15];

  if (POOL == 0) {
#pragma unroll
    for (int mt = 0; mt < 4; ++mt)
#pragma unroll
      for (int nt = 0; nt < NT; ++nt) {
        const int n = bn0 + wn * WTN + nt * 16 + mn15;
#pragma unroll
        for (int r = 0; r < 4; ++r) {
          const size_t m = bm0 + wm * 64 + mt * 16 + (lane >> 4) * 4 + r;
          float v = fmaxf(acc[mt][nt][r] + bv[nt], 0.f);
          unsigned short h, l; bsplit(v, h, l);
          Ch[m * Ndim + n] = h;
          Cl[m * Ndim + n] = l;
        }
      }
  } else {  // POOL == 128 (loc L3)
    float part[NT];
#pragma unroll
    for (int nt = 0; nt < NT; ++nt) {
      float v = -1e30f;
#pragma unroll
      for (int mt = 0; mt < 4; ++mt)
#pragma unroll
        for (int r = 0; r < 4; ++r) v = fmaxf(v, acc[mt][nt][r]);
      v = fmaxf(v + bv[nt], 0.f);
      v = fmaxf(v, __shfl_xor(v, 16, 64));
      v = fmaxf(v, __shfl_xor(v, 32, 64));
      part[nt] = v;
      if (lane < 16) sPool[wid][nt * 16 + mn15] = v;
    }
    __syncthreads();
    if (wm == 0 && lane < 16) {
#pragma unroll
      for (int nt = 0; nt < NT; ++nt) {
        float v = fmaxf(part[nt], sPool[wid + 1][nt * 16 + mn15]);
        const int n = bn0 + wn * WTN + nt * 16 + mn15;
        if (Cf) Cf[(size_t)(bm0 / 128) * Ndim + n] = v;
      }
    }
  }
}

// ------------- fused head: glob0 -> glob1 -> cls, 1 block/batch --------
__global__ __launch_bounds__(256) void head_kernel(
    const float* __restrict__ pooled,
    const float* __restrict__ w0, const float* __restrict__ b0,
    const float* __restrict__ w1, const float* __restrict__ b1,
    const float* __restrict__ wc, const float* __restrict__ bc,
    float* __restrict__ out)
{
  __shared__ float sx[1024];
  __shared__ float sy[512];
  __shared__ float sz[256];
  const int b = blockIdx.x, t = threadIdx.x;
  for (int i = t; i < 1024; i += 256) sx[i] = pooled[(size_t)b * 1024 + i];
  __syncthreads();
  for (int o = t; o < 512; o += 256) {
    const float4* w4 = (const float4*)(w0 + (size_t)o * 1024);
    const float4* x4 = (const float4*)sx;
    float acc = 0.f;
#pragma unroll 4
    for (int k = 0; k < 256; ++k) {
      float4 w = w4[k], x = x4[k];
      acc += w.x * x.x + w.y * x.y + w.z * x.z + w.w * x.w;
    }
    sy[o] = fmaxf(acc + b0[o], 0.f);
  }
  __syncthreads();
  if (t < 256) {
    const float4* w4 = (const float4*)(w1 + (size_t)t * 512);
    const float4* y4 = (const float4*)sy;
    float acc = 0.f;
#pragma unroll 4
    for (int k = 0; k < 128; ++k) {
      float4 w = w4[k], y = y4[k];
      acc += w.x * y.x + w.y * y.y + w.z * y.z + w.w * y.w;
    }
    sz[t] = fmaxf(acc + b1[t], 0.f);
  }
  __syncthreads();
  if (t < 40) {
    const float4* w4 = (const float4*)(wc + (size_t)t * 256);
    const float4* z4 = (const float4*)sz;
    float acc = 0.f;
#pragma unroll 4
    for (int k = 0; k < 64; ++k) {
      float4 w = w4[k], z = z4[k];
      acc += w.x * z.x + w.y * z.y + w.z * z.z + w.w * z.w;
    }
    out[(size_t)b * 40 + t] = acc + bc[t];
  }
}

// =====================================================================
extern "C" void kernel_launch(void* const* d_in, const int* in_sizes, int n_in,
                              void* d_out, int out_size, void* d_ws, size_t ws_size,
                              hipStream_t stream)
{
  (void)in_sizes; (void)n_in; (void)out_size; (void)ws_size;

  const float* points  = (const float*)d_in[0];
  const float* sa1_w[3] = {(const float*)d_in[1], (const float*)d_in[3], (const float*)d_in[5]};
  const float* sa1_b[3] = {(const float*)d_in[2], (const float*)d_in[4], (const float*)d_in[6]};
  const float* sa2_w[3] = {(const float*)d_in[7], (const float*)d_in[9], (const float*)d_in[11]};
  const float* sa2_b[3] = {(const float*)d_in[8], (const float*)d_in[10], (const float*)d_in[12]};
  const float* loc_w[3] = {(const float*)d_in[13], (const float*)d_in[15], (const float*)d_in[17]};
  const float* loc_b[3] = {(const float*)d_in[14], (const float*)d_in[16], (const float*)d_in[18]};
  const float* glob_w0 = (const float*)d_in[19];
  const float* glob_b0 = (const float*)d_in[20];
  const float* glob_w1 = (const float*)d_in[21];
  const float* glob_b1 = (const float*)d_in[22];
  const float* cls_w   = (const float*)d_in[23];
  const float* cls_b   = (const float*)d_in[24];

  char* base = (char*)d_ws;
  size_t off = 0;
  auto alloc = [&](size_t nbytes) -> void* {
    void* p = base + off;
    off += (nbytes + 255) & ~(size_t)255;
    return p;
  };

  // loc ping-pong plane buffers
  const size_t XE = (size_t)4096 * 512;
  const size_t YE = (size_t)4096 * 256;
  unsigned short* Xh = (unsigned short*)alloc(XE * 2);
  unsigned short* Xl = (unsigned short*)alloc(XE * 2);
  unsigned short* Yh = (unsigned short*)alloc(YE * 2);
  unsigned short* Yl = (unsigned short*)alloc(YE * 2);
  unsigned short* f1h = (unsigned short*)alloc((size_t)16384 * 128 * 2);
  unsigned short* f1l = (unsigned short*)alloc((size_t)16384 * 128 * 2);
  unsigned short* f2h = (unsigned short*)alloc((size_t)4096 * 256 * 2);
  unsigned short* f2l = (unsigned short*)alloc((size_t)4096 * 256 * 2);

  // weight planes
  const int  wrows[9] = {64, 64, 128, 128, 128, 256, 256, 512, 1024};
  const int  wK[9]    = {3, 64, 64, 131, 128, 128, 256, 256, 512};
  const int  wKP[9]   = {32, 64, 64, 160, 128, 128, 256, 256, 512};
  const float* wsrc[9] = {sa1_w[0], sa1_w[1], sa1_w[2],
                          sa2_w[0], sa2_w[1], sa2_w[2],
                          loc_w[0], loc_w[1], loc_w[2]};
  unsigned short *wph[9], *wpl[9];
  WSplitArgs wa;
  int cum = 0;
  for (int s = 0; s < 9; ++s) {
    size_t e = (size_t)wrows[s] * wKP[s];
    wph[s] = (unsigned short*)alloc(e * 2);
    wpl[s] = (unsigned short*)alloc(e * 2);
    wa.src[s] = wsrc[s]; wa.h[s] = wph[s]; wa.l[s] = wpl[s];
    wa.K[s] = wK[s]; wa.KP[s] = wKP[s]; wa.cum[s] = cum;
    wa.perm[s] = (s == 3) ? 1 : 0;
    cum += wrows[s] * wKP[s];
  }
  wa.cum[9] = cum;

  float* nx1_aos = (float*)alloc((size_t)32 * 512 * 3 * 4);
  float* nx1_soa = (float*)alloc((size_t)32 * 512 * 3 * 4);
  int*   idx1    = (int*)  alloc((size_t)32 * 512 * 32 * 4);
  float* nx2_aos = (float*)alloc((size_t)32 * 128 * 3 * 4);
  float* nx2_soa = (float*)alloc((size_t)32 * 128 * 3 * 4);
  int*   idx2    = (int*)  alloc((size_t)32 * 128 * 64 * 4);
  float* pooled  = (float*)alloc((size_t)32 * 1024 * 4);

  const float r2a = (float)(0.2 * 0.2);
  const float r2b = (float)(0.4 * 0.4);

  wsplit_all<<<CDIV(cum, 256), 256, 0, stream>>>(wa);

  // ---------------- SA1 (+ embedded fps2 in leading 32 blocks) ----------
  fps_kernel<8192, 512, 512><<<32, 512, 0, stream>>>(points, 24576, 8192, nx1_aos, nx1_soa);
  ballq_wave<8192, 32, 512><<<32 * 512, 64, 0, stream>>>(points, 24576, 8192, nx1_aos, idx1, r2a);

  sa1_fused<<<32 + 4096, 256, 0, stream>>>(
      points, idx1, nx1_aos, sa1_w[0], sa1_b[0],
      wph[1], wpl[1], sa1_b[1], wph[2], wpl[2], sa1_b[2], f1h, f1l,
      nx1_soa, nx2_aos, nx2_soa);

  // ---------------- SA2 ----------------
  ballq_wave<512, 64, 128><<<32 * 128, 64, 0, stream>>>(nx1_soa, 1536, 512, nx2_aos, idx2, r2b);

  sa2_fused<<<4096, 256, 0, stream>>>(
      f1h, f1l, nx1_aos, nx2_aos, idx2,
      wph[3], wpl[3], sa2_b[0],
      wph[4], wpl[4], sa2_b[1],
      wph[5], wpl[5], sa2_b[2],
      f2h, f2l);

  // ---------------- loc MLP (fused global maxpool at L3) ----------------
  mfma_gemm<128, 0><<<dim3(2, 32), 256, 0, stream>>>(
      f2h, f2l, wph[6], wpl[6], loc_b[0], Yh, Yl, nullptr, 256, 256);
  mfma_gemm<128, 0><<<dim3(4, 32), 256, 0, stream>>>(
      Yh, Yl, wph[7], wpl[7], loc_b[1], Xh, Xl, nullptr, 256, 512);
  mfma_gemm<128, 128><<<dim3(8, 32), 256, 0, stream>>>(
      Xh, Xl, wph[8], wpl[8], loc_b[2], nullptr, nullptr, pooled, 512, 1024);

  // ---------------- fused head ----------------
  head_kernel<<<32, 256, 0, stream>>>(pooled, glob_w0, glob_b0,
                                      glob_w1, glob_b1, cls_w, cls_b, (float*)d_out);
}